// Round 10
// baseline (343.866 us; speedup 1.0000x reference)
//
#include <hip/hip_runtime.h>

#define BATCH 64
#define SEQ 729
#define DIM 64
#define NT 12       // k tiles of 64
#define STRB 72     // bf16 LDS row stride (Ks/Vs/Ps)
#define MSTR 68     // mask byte-row stride
#define OSTR 68     // epilogue fp32 dword-row stride

typedef __attribute__((ext_vector_type(8))) short bf16x8;
typedef __attribute__((ext_vector_type(4))) float f32x4;
// 4B-aligned vector views for the 729-strided global rows
typedef int   i32x4a __attribute__((ext_vector_type(4), aligned(4)));
typedef float f32x4a __attribute__((ext_vector_type(4), aligned(4)));

__device__ __forceinline__ unsigned short f2bf(float f) {
    unsigned int u = __float_as_uint(f);
    u += 0x7fffu + ((u >> 16) & 1u);   // round-to-nearest-even
    return (unsigned short)(u >> 16);
}

__device__ __forceinline__ unsigned long long pack4bf(float a, float b, float c, float d) {
    return (unsigned long long)f2bf(a)
         | ((unsigned long long)f2bf(b) << 16)
         | ((unsigned long long)f2bf(c) << 32)
         | ((unsigned long long)f2bf(d) << 48);
}

__device__ __forceinline__ float bf2f(unsigned int hi16) {
    return __uint_as_float(hi16 << 16);
}

// tanh(x) = 1 - 2/(exp2(2x*log2e)+1); fast_tanh(-1e9) = -1 exactly
__device__ __forceinline__ float fast_tanh(float x) {
    float e = __builtin_amdgcn_exp2f(x * 2.88539008177792681f);
    return 1.0f - 2.0f * __builtin_amdgcn_rcpf(e + 1.0f);
}

// Raw barrier WITHOUT the vmcnt(0) drain (round-5 win): only LDS fenced;
// global loads/stores stay in flight; counted vmcnt at register drains.
#define BAR() do { \
    asm volatile("s_waitcnt lgkmcnt(0)" ::: "memory"); \
    __builtin_amdgcn_s_barrier(); \
    __builtin_amdgcn_sched_barrier(0); \
} while (0)

// launch_bounds(256,3): only config the allocator handles without spilling
// (rounds 1-4/8/9 evidence: VGPR settles at 84, zero scratch).
__global__ __launch_bounds__(256, 3) void attn_kernel(
    const float* __restrict__ Qg, const float* __restrict__ Kg,
    const float* __restrict__ Vg, const int* __restrict__ Mg,
    float* __restrict__ Og, float* __restrict__ Ag)
{
    __shared__ __align__(16) unsigned char smem[50432];
    unsigned short* Ks0 = (unsigned short*)(smem);           // [k][d] bf16 (9216)
    unsigned short* Vs0 = (unsigned short*)(smem + 9216);    // [d][k] bf16 (9216)
    unsigned short* Ks1 = (unsigned short*)(smem + 18432);   // dbuf copies
    unsigned short* Vs1 = (unsigned short*)(smem + 27648);
    unsigned short* Ps  = (unsigned short*)(smem + 36864);   // Q bf16, then P bf16 (9216)
    unsigned char*  Mb8 = smem + 46080;                      // [q][k] mask bytes (4352)
    float* Ostage = (float*)smem;   // epilogue overlay on Ks0/Vs0 (17408 <= 18432)

    const int tid = threadIdx.x;
    const int q0  = blockIdx.x * 64;
    const int b   = blockIdx.y;

    const float* Qb = Qg + (size_t)b * SEQ * DIM;
    const float* Kb = Kg + (size_t)b * SEQ * DIM;
    const float* Vb = Vg + (size_t)b * SEQ * DIM;
    const int*   Mb = Mg + (size_t)b * SEQ * SEQ;
    float* Ob = Og + (size_t)b * SEQ * DIM;
    float* Ab = Ag + (size_t)b * SEQ * SEQ;

    const int lane = tid & 63;
    const int quad = lane >> 4;
    const int l15  = lane & 15;
    const int qrow = (tid >> 6) * 16;      // wave's q-strip base (local)

    // block-cooperative staging geometry: 16 consecutive threads cover one
    // row's 64 cols -> 256B contiguous segments, float4 per lane
    const int rr = tid >> 4;               // row group 0..15 (+16*i)
    const int cc = (tid & 15) * 4;         // col (floats)
    const int vd0 = (tid & 15) * 4;        // V: dims
    const int vk0 = (tid >> 4) * 4;        // V: k rows
    // wave-private row geometry: 16 lanes cover one row's 64 cols
    const int prow = qrow + (lane >> 4);   // + 4*i -> rows qrow..qrow+15
    const int pcol = (lane & 15) * 4;

    float4 kr[4], vr[4];
    i32x4a mr[4];
    // touch-prefetch stream state (3 persistent VGPRs): primes L2 for tile
    // t+3; consumed (keep-alive) one phase later -> zero-stall retirement.
    float tkP = 0.f, tvP = 0.f;
    int   tmP = 0;
    const int trow = tid >> 2;             // 64 rows x 4 lines/row
    const int toff = (tid & 3) * 16;       // line within row (16 dwords = 64B)

    auto load_k = [&](int k0n) {
        #pragma unroll
        for (int i = 0; i < 4; ++i) {
            int gk = k0n + rr + 16 * i;
            kr[i] = (gk < SEQ) ? *(const float4*)(Kb + gk * DIM + cc)
                               : float4{0, 0, 0, 0};
        }
    };
    auto load_v = [&](int k0n) {
        #pragma unroll
        for (int i = 0; i < 4; ++i) {
            int gk = k0n + vk0 + i;
            vr[i] = (gk < SEQ) ? *(const float4*)(Vb + gk * DIM + vd0)
                               : float4{0, 0, 0, 0};
        }
    };
    auto load_mask = [&](int k0n) {
        #pragma unroll
        for (int i = 0; i < 4; ++i) {
            int gq = q0 + prow + 4 * i;
            int gk = k0n + pcol;
            if (gq < SEQ && gk + 3 < SEQ) {
                mr[i] = *(const i32x4a*)(Mb + (size_t)gq * SEQ + gk);
            } else if (gq < SEQ) {
                i32x4a t;
                #pragma unroll
                for (int e = 0; e < 4; ++e)
                    t[e] = (gk + e < SEQ) ? Mb[(size_t)gq * SEQ + gk + e] : 0;
                mr[i] = t;
            } else {
                mr[i] = i32x4a{0, 0, 0, 0};
            }
        }
    };
    auto drain_mask = [&]() {   // pack 0/1 ints to bytes; wave-private rows
        #pragma unroll
        for (int i = 0; i < 4; ++i) {
            unsigned int mb = (unsigned)(mr[i][0] & 1)
                            | ((unsigned)(mr[i][1] & 1) << 8)
                            | ((unsigned)(mr[i][2] & 1) << 16)
                            | ((unsigned)(mr[i][3] & 1) << 24);
            *(unsigned int*)&Mb8[(prow + 4 * i) * MSTR + pcol] = mb;
        }
    };
    auto drain_kv = [&](unsigned short* Kd, unsigned short* Vd) {
        #pragma unroll
        for (int i = 0; i < 4; ++i)
            *(unsigned long long*)&Kd[(rr + 16 * i) * STRB + cc] =
                pack4bf(kr[i].x, kr[i].y, kr[i].z, kr[i].w);
        #pragma unroll
        for (int j = 0; j < 4; ++j) {
            float v0 = j==0?vr[0].x:j==1?vr[0].y:j==2?vr[0].z:vr[0].w;
            float v1 = j==0?vr[1].x:j==1?vr[1].y:j==2?vr[1].z:vr[1].w;
            float v2 = j==0?vr[2].x:j==1?vr[2].y:j==2?vr[2].z:vr[2].w;
            float v3 = j==0?vr[3].x:j==1?vr[3].y:j==2?vr[3].z:vr[3].w;
            *(unsigned long long*)&Vd[(vd0 + j) * STRB + vk0] = pack4bf(v0, v1, v2, v3);
        }
    };
    // touch one dword per 64B line of tile k0n's K, V and mask chunk:
    // exactly the lines the real loads will need two phases later.
    auto touch = [&](int k0n) {
        int krow = k0n + trow;
        tkP = (krow < SEQ) ? Kb[krow * DIM + toff] : 0.f;
        tvP = (krow < SEQ) ? Vb[krow * DIM + toff] : 0.f;
        int mrow = q0 + trow;
        int mcol = k0n + toff;
        tmP = (mrow < SEQ && mcol < SEQ) ? Mb[(size_t)mrow * SEQ + mcol] : 0;
    };

    // ---- prologue: issue tile-0 loads first (max lead), stage Q ----
    load_k(0); load_v(0); load_mask(0);
    #pragma unroll
    for (int i = 0; i < 4; ++i) {
        int gq = q0 + rr + 16 * i;
        float4 x = (gq < SEQ) ? *(const float4*)(Qb + gq * DIM + cc)
                              : float4{0, 0, 0, 0};
        *(unsigned long long*)&Ps[(rr + 16 * i) * STRB + cc] = pack4bf(x.x, x.y, x.z, x.w);
    }
    BAR();   // Qs visible (lgkmcnt only)

    // hoist loop-invariant Q fragments; Ps becomes the P bf16 buffer
    const bf16x8 aq0 = *(const bf16x8*)&Ps[(qrow + l15) * STRB + quad * 8];
    const bf16x8 aq1 = *(const bf16x8*)&Ps[(qrow + l15) * STRB + 32 + quad * 8];

    // drain tile 0 -> buf0; issue tile-1 loads; prime tile-2 lines
    drain_mask();
    drain_kv(Ks0, Vs0);
    load_k(64); load_v(64); load_mask(64);
    touch(128);
    BAR();   // buf0 visible

    f32x4 oacc[4];
    #pragma unroll
    for (int dt = 0; dt < 4; ++dt) {
        oacc[dt][0]=0.f; oacc[dt][1]=0.f; oacc[dt][2]=0.f; oacc[dt][3]=0.f;
    }

    for (int t = 0; t < NT; ++t) {
        const int k0 = t * 64;
        const unsigned short* KsC = (t & 1) ? Ks1 : Ks0;   // uniform selects
        const unsigned short* VsC = (t & 1) ? Vs1 : Vs0;
        unsigned short* KsN = (t & 1) ? Ks0 : Ks1;
        unsigned short* VsN = (t & 1) ? Vs0 : Vs1;

        // ---- QK^T (starts immediately at phase start: no drain ahead) ----
        f32x4 sacc[4];
        __builtin_amdgcn_s_setprio(1);
        #pragma unroll
        for (int n = 0; n < 4; ++n) {
            bf16x8 bk0 = *(const bf16x8*)&KsC[(n * 16 + l15) * STRB + quad * 8];
            bf16x8 bk1 = *(const bf16x8*)&KsC[(n * 16 + l15) * STRB + 32 + quad * 8];
            f32x4 c; c[0]=0.f; c[1]=0.f; c[2]=0.f; c[3]=0.f;
            c = __builtin_amdgcn_mfma_f32_16x16x32_bf16(aq0, bk0, c, 0, 0, 0);
            c = __builtin_amdgcn_mfma_f32_16x16x32_bf16(aq1, bk1, c, 0, 0, 0);
            sacc[n] = c;
        }
        __builtin_amdgcn_s_setprio(0);

        // ---- scale, mask (LDS bytes), tanh, zero-diag; write P bf16 ----
        #pragma unroll
        for (int n = 0; n < 4; ++n) {
            int col = n * 16 + l15;
            int gk  = k0 + col;
            #pragma unroll
            for (int r = 0; r < 4; ++r) {
                int qloc = qrow + quad * 4 + r;
                int gq = q0 + qloc;
                int m = Mb8[qloc * MSTR + col];
                float sv = sacc[n][r] * 0.125f;        // 1/sqrt(64)
                // masked: tanh(-1e9) == -1 exactly via exp2 underflow
                float p = fast_tanh((m == 0) ? -1e9f : sv);
                if (gq == gk || gk >= SEQ) p = 0.0f;   // ignore_diag + padding
                Ps[qloc * STRB + col] = f2bf(p);
            }
        }

        // ---- PV (wave-private P rows: no barrier needed) ----
        const bf16x8 ap0 = *(const bf16x8*)&Ps[(qrow + l15) * STRB + quad * 8];
        const bf16x8 ap1 = *(const bf16x8*)&Ps[(qrow + l15) * STRB + 32 + quad * 8];
        __builtin_amdgcn_s_setprio(1);
        #pragma unroll
        for (int dt = 0; dt < 4; ++dt) {
            bf16x8 bv0 = *(const bf16x8*)&VsC[(dt * 16 + l15) * STRB + quad * 8];
            bf16x8 bv1 = *(const bf16x8*)&VsC[(dt * 16 + l15) * STRB + 32 + quad * 8];
            oacc[dt] = __builtin_amdgcn_mfma_f32_16x16x32_bf16(ap0, bv0, oacc[dt], 0, 0, 0);
            oacc[dt] = __builtin_amdgcn_mfma_f32_16x16x32_bf16(ap1, bv1, oacc[dt], 0, 0, 0);
        }
        __builtin_amdgcn_s_setprio(0);

        // ---- attention write-out from bf16 P (values PV consumes):
        //      wave-private rows, row-contiguous float4 -> 256B segments ----
        #pragma unroll
        for (int i = 0; i < 4; ++i) {
            int row = prow + 4 * i;
            int gq  = q0 + row;
            int gk  = k0 + pcol;
            unsigned long long w = *(const unsigned long long*)&Ps[row * STRB + pcol];
            f32x4 pv;
            pv[0] = bf2f((unsigned)(w      ) & 0xffffu);
            pv[1] = bf2f((unsigned)(w >> 16) & 0xffffu);
            pv[2] = bf2f((unsigned)(w >> 32) & 0xffffu);
            pv[3] = bf2f((unsigned)(w >> 48) & 0xffffu);
            if (gq < SEQ) {
                if (gk + 3 < SEQ) {
                    *(f32x4a*)(Ab + (size_t)gq * SEQ + gk) = pv;
                } else {
                    #pragma unroll
                    for (int e = 0; e < 4; ++e)
                        if (gk + e < SEQ) Ab[(size_t)gq * SEQ + gk + e] = pv[e];
                }
            }
        }

        // ---- drain tile t+1 (full compute phase of vmcnt lead); issue t+2
        //      real loads; retire last phase's touches; touch t+3 lines ----
        if (t + 1 < NT) {
            drain_mask();
            drain_kv(KsN, VsN);
            if (t + 2 < NT) {
                load_k(k0 + 128); load_v(k0 + 128); load_mask(k0 + 128);
            }
            // retire previous touches (arrived a phase ago: no stall);
            // keep-alive so the loads aren't DCE'd (rule #17)
            asm volatile("" :: "v"(tkP), "v"(tvP), "v"(tmP));
            if (t + 3 < NT) touch(k0 + 192);   // younger than real loads in
                                               // the vmcnt queue -> never
                                               // blocks a counted drain wait
            BAR();   // single barrier per phase (round-8 structure)
        }
    }
    asm volatile("" :: "v"(tkP), "v"(tvP), "v"(tmP));

    // ---- O epilogue: all waves done with Ks/Vs -> overlay-stage
    //      (wave-private rows), then row-contiguous float4 stores ----
    BAR();
    #pragma unroll
    for (int dt = 0; dt < 4; ++dt)
        #pragma unroll
        for (int r = 0; r < 4; ++r)
            Ostage[(qrow + quad * 4 + r) * OSTR + dt * 16 + l15] = oacc[dt][r];
    // wave-private strip: no further barrier needed
    #pragma unroll
    for (int i = 0; i < 4; ++i) {
        int row = prow + 4 * i;
        int gq  = q0 + row;
        f32x4 ov = *(const f32x4*)&Ostage[row * OSTR + pcol];
        if (gq < SEQ) *(f32x4*)(Ob + (size_t)gq * DIM + pcol) = ov;  // 16B-aligned
    }
}

extern "C" void kernel_launch(void* const* d_in, const int* in_sizes, int n_in,
                              void* d_out, int out_size, void* d_ws, size_t ws_size,
                              hipStream_t stream) {
    const float* Q = (const float*)d_in[0];
    const float* K = (const float*)d_in[1];
    const float* V = (const float*)d_in[2];
    const int*   M = (const int*)d_in[3];
    float* Out  = (float*)d_out;
    float* Attn = Out + (size_t)BATCH * SEQ * DIM;   // tuple order: (out, attention)
    dim3 grid(NT, BATCH);
    attn_kernel<<<grid, 256, 0, stream>>>(Q, K, V, M, Out, Attn);
}

// Round 11
// 323.213 us; speedup vs baseline: 1.0639x; 1.0639x over previous
//
#include <hip/hip_runtime.h>

#define BATCH 64
#define SEQ 729
#define DIM 64
#define NT 12       // k tiles of 64
#define STRB 72     // bf16 LDS row stride (Ks/Vs/Ps)
#define MSTR 68     // mask byte-row stride
#define OSTR 68     // epilogue fp32 dword-row stride

typedef __attribute__((ext_vector_type(8))) short bf16x8;
typedef __attribute__((ext_vector_type(4))) float f32x4;
// 4B-aligned vector views for the 729-strided global rows
typedef int   i32x4a __attribute__((ext_vector_type(4), aligned(4)));
typedef float f32x4a __attribute__((ext_vector_type(4), aligned(4)));

__device__ __forceinline__ unsigned short f2bf(float f) {
    unsigned int u = __float_as_uint(f);
    u += 0x7fffu + ((u >> 16) & 1u);   // round-to-nearest-even
    return (unsigned short)(u >> 16);
}

__device__ __forceinline__ unsigned long long pack4bf(float a, float b, float c, float d) {
    return (unsigned long long)f2bf(a)
         | ((unsigned long long)f2bf(b) << 16)
         | ((unsigned long long)f2bf(c) << 32)
         | ((unsigned long long)f2bf(d) << 48);
}

__device__ __forceinline__ float bf2f(unsigned int hi16) {
    return __uint_as_float(hi16 << 16);
}

// tanh(x) = 1 - 2/(exp2(2x*log2e)+1); fast_tanh(-1e9) = -1 exactly
__device__ __forceinline__ float fast_tanh(float x) {
    float e = __builtin_amdgcn_exp2f(x * 2.88539008177792681f);
    return 1.0f - 2.0f * __builtin_amdgcn_rcpf(e + 1.0f);
}

// Raw barrier WITHOUT the vmcnt(0) drain (round-5 win): only LDS fenced;
// global loads/stores stay in flight; counted vmcnt at register drains.
#define BAR() do { \
    asm volatile("s_waitcnt lgkmcnt(0)" ::: "memory"); \
    __builtin_amdgcn_s_barrier(); \
    __builtin_amdgcn_sched_barrier(0); \
} while (0)

// launch_bounds(256,3): only config the allocator handles without spilling
// (rounds 1-4/8/9 evidence: VGPR settles at 84, zero scratch).
__global__ __launch_bounds__(256, 3) void attn_kernel(
    const float* __restrict__ Qg, const float* __restrict__ Kg,
    const float* __restrict__ Vg, const int* __restrict__ Mg,
    float* __restrict__ Og, float* __restrict__ Ag)
{
    __shared__ __align__(16) unsigned char smem[50432];
    unsigned short* Ks0 = (unsigned short*)(smem);           // [k][d] bf16 (9216)
    unsigned short* Vs0 = (unsigned short*)(smem + 9216);    // [d][k] bf16 (9216)
    unsigned short* Ks1 = (unsigned short*)(smem + 18432);   // dbuf copies
    unsigned short* Vs1 = (unsigned short*)(smem + 27648);
    unsigned short* Ps  = (unsigned short*)(smem + 36864);   // Q bf16, then P bf16 (9216)
    unsigned char*  Mb8 = smem + 46080;                      // [q][k] mask bytes (4352)
    float* Ostage = (float*)smem;   // epilogue overlay on Ks0/Vs0 (17408 <= 18432)

    const int tid = threadIdx.x;
    const int q0  = blockIdx.x * 64;
    const int b   = blockIdx.y;

    const float* Qb = Qg + (size_t)b * SEQ * DIM;
    const float* Kb = Kg + (size_t)b * SEQ * DIM;
    const float* Vb = Vg + (size_t)b * SEQ * DIM;
    const int*   Mb = Mg + (size_t)b * SEQ * SEQ;
    float* Ob = Og + (size_t)b * SEQ * DIM;
    float* Ab = Ag + (size_t)b * SEQ * SEQ;

    const int lane = tid & 63;
    const int quad = lane >> 4;
    const int l15  = lane & 15;
    const int qrow = (tid >> 6) * 16;      // wave's q-strip base (local)

    // block-cooperative staging geometry: 16 consecutive threads cover one
    // row's 64 cols -> 256B contiguous segments, float4 per lane
    const int rr = tid >> 4;               // row group 0..15 (+16*i)
    const int cc = (tid & 15) * 4;         // col (floats)
    const int vd0 = (tid & 15) * 4;        // V: dims
    const int vk0 = (tid >> 4) * 4;        // V: k rows
    // wave-private row geometry: 16 lanes cover one row's 64 cols
    const int prow = qrow + (lane >> 4);   // + 4*i -> rows qrow..qrow+15
    const int pcol = (lane & 15) * 4;

    float4 kr[4], vr[4];
    i32x4a mr[4];

    auto load_k = [&](int k0n) {
        #pragma unroll
        for (int i = 0; i < 4; ++i) {
            int gk = k0n + rr + 16 * i;
            kr[i] = (gk < SEQ) ? *(const float4*)(Kb + gk * DIM + cc)
                               : float4{0, 0, 0, 0};
        }
    };
    auto load_v = [&](int k0n) {
        #pragma unroll
        for (int i = 0; i < 4; ++i) {
            int gk = k0n + vk0 + i;
            vr[i] = (gk < SEQ) ? *(const float4*)(Vb + gk * DIM + vd0)
                               : float4{0, 0, 0, 0};
        }
    };
    auto load_mask = [&](int k0n) {
        #pragma unroll
        for (int i = 0; i < 4; ++i) {
            int gq = q0 + prow + 4 * i;
            int gk = k0n + pcol;
            if (gq < SEQ && gk + 3 < SEQ) {
                mr[i] = *(const i32x4a*)(Mb + (size_t)gq * SEQ + gk);
            } else if (gq < SEQ) {
                i32x4a t;
                #pragma unroll
                for (int e = 0; e < 4; ++e)
                    t[e] = (gk + e < SEQ) ? Mb[(size_t)gq * SEQ + gk + e] : 0;
                mr[i] = t;
            } else {
                mr[i] = i32x4a{0, 0, 0, 0};
            }
        }
    };
    auto drain_mask = [&]() {   // pack 0/1 ints to bytes; wave-private rows
        #pragma unroll
        for (int i = 0; i < 4; ++i) {
            unsigned int mb = (unsigned)(mr[i][0] & 1)
                            | ((unsigned)(mr[i][1] & 1) << 8)
                            | ((unsigned)(mr[i][2] & 1) << 16)
                            | ((unsigned)(mr[i][3] & 1) << 24);
            *(unsigned int*)&Mb8[(prow + 4 * i) * MSTR + pcol] = mb;
        }
    };
    auto drain_k = [&](unsigned short* Kd) {
        #pragma unroll
        for (int i = 0; i < 4; ++i)
            *(unsigned long long*)&Kd[(rr + 16 * i) * STRB + cc] =
                pack4bf(kr[i].x, kr[i].y, kr[i].z, kr[i].w);
    };
    auto drain_v = [&](unsigned short* Vd) {
        #pragma unroll
        for (int j = 0; j < 4; ++j) {
            float v0 = j==0?vr[0].x:j==1?vr[0].y:j==2?vr[0].z:vr[0].w;
            float v1 = j==0?vr[1].x:j==1?vr[1].y:j==2?vr[1].z:vr[1].w;
            float v2 = j==0?vr[2].x:j==1?vr[2].y:j==2?vr[2].z:vr[2].w;
            float v3 = j==0?vr[3].x:j==1?vr[3].y:j==2?vr[3].z:vr[3].w;
            *(unsigned long long*)&Vd[(vd0 + j) * STRB + vk0] = pack4bf(v0, v1, v2, v3);
        }
    };

    // ---- prologue: issue tile-0 loads first (max lead), stage Q ----
    load_k(0); load_v(0); load_mask(0);
    #pragma unroll
    for (int i = 0; i < 4; ++i) {
        int gq = q0 + rr + 16 * i;
        float4 x = (gq < SEQ) ? *(const float4*)(Qb + gq * DIM + cc)
                              : float4{0, 0, 0, 0};
        *(unsigned long long*)&Ps[(rr + 16 * i) * STRB + cc] = pack4bf(x.x, x.y, x.z, x.w);
    }
    BAR();   // Qs visible (lgkmcnt only)

    // hoist loop-invariant Q fragments; Ps becomes the P bf16 buffer
    const bf16x8 aq0 = *(const bf16x8*)&Ps[(qrow + l15) * STRB + quad * 8];
    const bf16x8 aq1 = *(const bf16x8*)&Ps[(qrow + l15) * STRB + 32 + quad * 8];

    // drain tile 0 -> buf0; issue tile-1 loads
    drain_mask();
    drain_k(Ks0);
    drain_v(Vs0);
    load_k(64); load_v(64); load_mask(64);
    BAR();   // buf0 visible

    f32x4 oacc[4];
    #pragma unroll
    for (int dt = 0; dt < 4; ++dt) {
        oacc[dt][0]=0.f; oacc[dt][1]=0.f; oacc[dt][2]=0.f; oacc[dt][3]=0.f;
    }

    for (int t = 0; t < NT; ++t) {
        const int k0 = t * 64;
        const unsigned short* KsC = (t & 1) ? Ks1 : Ks0;   // uniform selects
        const unsigned short* VsC = (t & 1) ? Vs1 : Vs0;
        unsigned short* KsN = (t & 1) ? Ks0 : Ks1;
        unsigned short* VsN = (t & 1) ? Vs0 : Vs1;

        // ---- burst 1 (phase start): K drain + K issue. K(t+1)'s loads have
        //      been in flight a full phase -> the counted vmcnt wait is free.
        //      Prev BAR guarantees all waves finished reading KsN (tile t-1).
        if (t + 1 < NT) drain_k(KsN);
        if (t + 2 < NT) load_k(k0 + 128);

        // ---- QK^T on the current buffer ----
        f32x4 sacc[4];
        #pragma unroll
        for (int n = 0; n < 4; ++n) {
            bf16x8 bk0 = *(const bf16x8*)&KsC[(n * 16 + l15) * STRB + quad * 8];
            bf16x8 bk1 = *(const bf16x8*)&KsC[(n * 16 + l15) * STRB + 32 + quad * 8];
            f32x4 c; c[0]=0.f; c[1]=0.f; c[2]=0.f; c[3]=0.f;
            c = __builtin_amdgcn_mfma_f32_16x16x32_bf16(aq0, bk0, c, 0, 0, 0);
            c = __builtin_amdgcn_mfma_f32_16x16x32_bf16(aq1, bk1, c, 0, 0, 0);
            sacc[n] = c;
        }

        // ---- scale, mask (LDS bytes), tanh, zero-diag; write P bf16 ----
        #pragma unroll
        for (int n = 0; n < 4; ++n) {
            int col = n * 16 + l15;
            int gk  = k0 + col;
            #pragma unroll
            for (int r = 0; r < 4; ++r) {
                int qloc = qrow + quad * 4 + r;
                int gq = q0 + qloc;
                int m = Mb8[qloc * MSTR + col];
                float sv = sacc[n][r] * 0.125f;        // 1/sqrt(64)
                // masked: tanh(-1e9) == -1 exactly via exp2 underflow
                float p = fast_tanh((m == 0) ? -1e9f : sv);
                if (gq == gk || gk >= SEQ) p = 0.0f;   // ignore_diag + padding
                Ps[qloc * STRB + col] = f2bf(p);
            }
        }

        // ---- burst 2 (mid-phase): attention stores from bf16 P ----
        //      wave-private rows, row-contiguous float4 -> 256B segments
        #pragma unroll
        for (int i = 0; i < 4; ++i) {
            int row = prow + 4 * i;
            int gq  = q0 + row;
            int gk  = k0 + pcol;
            unsigned long long w = *(const unsigned long long*)&Ps[row * STRB + pcol];
            f32x4 pv;
            pv[0] = bf2f((unsigned)(w      ) & 0xffffu);
            pv[1] = bf2f((unsigned)(w >> 16) & 0xffffu);
            pv[2] = bf2f((unsigned)(w >> 32) & 0xffffu);
            pv[3] = bf2f((unsigned)(w >> 48) & 0xffffu);
            if (gq < SEQ) {
                if (gk + 3 < SEQ) {
                    *(f32x4a*)(Ab + (size_t)gq * SEQ + gk) = pv;
                } else {
                    #pragma unroll
                    for (int e = 0; e < 4; ++e)
                        if (gk + e < SEQ) Ab[(size_t)gq * SEQ + gk + e] = pv[e];
                }
            }
        }

        // ---- PV (wave-private P rows: no barrier needed) ----
        const bf16x8 ap0 = *(const bf16x8*)&Ps[(qrow + l15) * STRB + quad * 8];
        const bf16x8 ap1 = *(const bf16x8*)&Ps[(qrow + l15) * STRB + 32 + quad * 8];
        #pragma unroll
        for (int dt = 0; dt < 4; ++dt) {
            bf16x8 bv0 = *(const bf16x8*)&VsC[(dt * 16 + l15) * STRB + quad * 8];
            bf16x8 bv1 = *(const bf16x8*)&VsC[(dt * 16 + l15) * STRB + 32 + quad * 8];
            oacc[dt] = __builtin_amdgcn_mfma_f32_16x16x32_bf16(ap0, bv0, oacc[dt], 0, 0, 0);
            oacc[dt] = __builtin_amdgcn_mfma_f32_16x16x32_bf16(ap1, bv1, oacc[dt], 0, 0, 0);
        }

        // ---- burst 3 (phase end): V + mask drain, V + mask issue ----
        if (t + 1 < NT) {
            drain_mask();
            drain_v(VsN);
            if (t + 2 < NT) {
                load_v(k0 + 128); load_mask(k0 + 128);
            }
            BAR();   // single barrier per phase (round-8 structure)
        }
    }

    // ---- O epilogue: all waves done with Ks/Vs -> overlay-stage
    //      (wave-private rows), then row-contiguous float4 stores ----
    BAR();
    #pragma unroll
    for (int dt = 0; dt < 4; ++dt)
        #pragma unroll
        for (int r = 0; r < 4; ++r)
            Ostage[(qrow + quad * 4 + r) * OSTR + dt * 16 + l15] = oacc[dt][r];
    // wave-private strip: no further barrier needed
    #pragma unroll
    for (int i = 0; i < 4; ++i) {
        int row = prow + 4 * i;
        int gq  = q0 + row;
        f32x4 ov = *(const f32x4*)&Ostage[row * OSTR + pcol];
        if (gq < SEQ) *(f32x4*)(Ob + (size_t)gq * DIM + pcol) = ov;  // 16B-aligned
    }
}

extern "C" void kernel_launch(void* const* d_in, const int* in_sizes, int n_in,
                              void* d_out, int out_size, void* d_ws, size_t ws_size,
                              hipStream_t stream) {
    const float* Q = (const float*)d_in[0];
    const float* K = (const float*)d_in[1];
    const float* V = (const float*)d_in[2];
    const int*   M = (const int*)d_in[3];
    float* Out  = (float*)d_out;
    float* Attn = Out + (size_t)BATCH * SEQ * DIM;   // tuple order: (out, attention)
    dim3 grid(NT, BATCH);
    attn_kernel<<<grid, 256, 0, stream>>>(Q, K, V, M, Out, Attn);
}